// Round 1
// baseline (580.011 us; speedup 1.0000x reference)
//
#include <hip/hip_runtime.h>
#include <stdint.h>

// Problem constants
#define BB 2
#define SS 2048
#define HID 2048
#define NH 16
#define DD 128
#define NKV 4

typedef unsigned short u16;
typedef __attribute__((ext_vector_type(8))) short short8;   // 8 x bf16 (4 VGPRs) MFMA A/B frag
typedef __attribute__((ext_vector_type(4))) float f32x4;    // MFMA C/D frag

__device__ __forceinline__ u16 f2bf(float x) {
    union { float f; unsigned u; } v; v.f = x;
    unsigned u = v.u;
    return (u16)((u + 0x7FFFu + ((u >> 16) & 1u)) >> 16);   // RNE
}

// async global->LDS, 16B per lane. lds ptr must be wave-uniform (HW adds lane*16).
__device__ __forceinline__ void async_lds16(const void* g, void* l) {
    __builtin_amdgcn_global_load_lds(
        (const __attribute__((address_space(1))) void*)(uintptr_t)g,
        (__attribute__((address_space(3))) void*)(uintptr_t)l,
        16, 0, 0);
}

// ---------------- elementwise fp32 -> bf16 ----------------
__global__ __launch_bounds__(256) void k_convert(const float* __restrict__ in,
                                                 u16* __restrict__ out, int n4) {
    int i = blockIdx.x * 256 + threadIdx.x;
    if (i >= n4) return;
    float4 v = ((const float4*)in)[i];
    uint2 o;
    o.x = (unsigned)f2bf(v.x) | ((unsigned)f2bf(v.y) << 16);
    o.y = (unsigned)f2bf(v.z) | ((unsigned)f2bf(v.w) << 16);
    ((uint2*)out)[i] = o;
}

// ---------------- weight transpose+convert: src fp32 [K][N] -> dst bf16 [N][K] ----------------
__global__ __launch_bounds__(256) void k_transpose_w(const float* __restrict__ src,
                                                     u16* __restrict__ dst, int K, int N) {
    __shared__ float tile[32][33];
    const int n0 = blockIdx.x * 32, k0 = blockIdx.y * 32;
    const int c = threadIdx.x & 31, r = threadIdx.x >> 5;
#pragma unroll
    for (int i = 0; i < 32; i += 8)
        tile[r + i][c] = src[(size_t)(k0 + r + i) * N + n0 + c];
    __syncthreads();
#pragma unroll
    for (int i = 0; i < 32; i += 8)
        dst[(size_t)(n0 + r + i) * K + k0 + c] = f2bf(tile[c][r + i]);
}

// ---------------- bf16 GEMM: C[M][N] = A[M][K] * Bt[N][K]^T + bias ----------------
// 128x128 tile, BK=32, 4 waves (2x2), each wave 4x4 16x16x32 MFMA tiles.
// LDS chunk swizzle s(row)=(row>>1)&3 -> 2-way bank aliasing on ds_read_b128 (free).
__global__ __launch_bounds__(256) void k_gemm_bt(const u16* __restrict__ A,
                                                 const u16* __restrict__ Bt,
                                                 const float* __restrict__ bias,
                                                 float* __restrict__ C,
                                                 int M, int N, int K) {
    __shared__ u16 As[128 * 32];
    __shared__ u16 Bs[128 * 32];

    const int tid = threadIdx.x;
    const int lane = tid & 63, wave = tid >> 6;
    const int bm = blockIdx.y * 128, bn = blockIdx.x * 128;

    // staging map: thread -> (row = tid>>2, chunk position = tid&3)
    const int srow = tid >> 2, spos = tid & 3;
    const int c0 = (spos ^ ((srow >> 1) & 3)) * 8;   // swizzled global chunk (same for row+64)
    const u16* gA0 = A  + (size_t)(bm + srow) * K + c0;
    const u16* gA1 = A  + (size_t)(bm + 64 + srow) * K + c0;
    const u16* gB0 = Bt + (size_t)(bn + srow) * K + c0;
    const u16* gB1 = Bt + (size_t)(bn + 64 + srow) * K + c0;

    const int r = lane & 15, q4 = lane >> 4;
    const int wm = (wave & 1) * 64, wn = (wave >> 1) * 64;

    int aoff[4], boff[4];
#pragma unroll
    for (int i = 0; i < 4; i++) {
        const int ar = wm + i * 16 + r;
        aoff[i] = ar * 32 + ((q4 ^ ((ar >> 1) & 3)) << 3);
        const int br = wn + i * 16 + r;
        boff[i] = br * 32 + ((q4 ^ ((br >> 1) & 3)) << 3);
    }

    f32x4 acc[4][4] = {};

    for (int kb = 0; kb < K; kb += 32) {
        async_lds16(gA0, As + wave * 512);
        async_lds16(gA1, As + 2048 + wave * 512);
        async_lds16(gB0, Bs + wave * 512);
        async_lds16(gB1, Bs + 2048 + wave * 512);
        gA0 += 32; gA1 += 32; gB0 += 32; gB1 += 32;
        __syncthreads();

        short8 av[4], bv_[4];
#pragma unroll
        for (int i = 0; i < 4; i++) av[i] = *(const short8*)(As + aoff[i]);
#pragma unroll
        for (int j = 0; j < 4; j++) bv_[j] = *(const short8*)(Bs + boff[j]);
#pragma unroll
        for (int i = 0; i < 4; i++)
#pragma unroll
            for (int j = 0; j < 4; j++)
                acc[i][j] = __builtin_amdgcn_mfma_f32_16x16x32_bf16(av[i], bv_[j], acc[i][j], 0, 0, 0);
        __syncthreads();
    }

#pragma unroll
    for (int j = 0; j < 4; j++) {
        const int col = bn + wn + j * 16 + r;
        const float bb = bias[col];
#pragma unroll
        for (int i = 0; i < 4; i++) {
            const int row = bm + wm + i * 16 + q4 * 4;
#pragma unroll
            for (int g = 0; g < 4; g++)
                C[(size_t)(row + g) * N + col] = acc[i][j][g] + bb;
        }
    }
}

// ---------------- RoPE q: fp32 [B*S][H*D] -> bf16 [B][H][S][D] ----------------
__global__ __launch_bounds__(256) void k_rope_q(const float* __restrict__ qf,
                                                const float* __restrict__ fc,
                                                const float* __restrict__ fs,
                                                u16* __restrict__ out) {
    const int t = blockIdx.x * 256 + threadIdx.x;     // 4194304 pairs
    const int row = t >> 10;                          // b*S+s
    const int w = t & 1023;                           // h*64+i
    const int h = w >> 6, i = w & 63;
    const int b = row >> 11, s = row & 2047;
    const float2 p = ((const float2*)qf)[(size_t)row * 1024 + w];
    const float c = fc[s * 64 + i], sn = fs[s * 64 + i];
    const float re = p.x * c - p.y * sn;
    const float im = p.x * sn + p.y * c;
    const unsigned val = (unsigned)f2bf(re) | ((unsigned)f2bf(im) << 16);
    ((unsigned*)out)[(((size_t)(b * NH + h) * SS + s) << 6) + i] = val;
}

// ---------------- RoPE k: fp32 [B*S][KV*D] -> bf16 [B][KV][S][D] ----------------
__global__ __launch_bounds__(256) void k_rope_k(const float* __restrict__ kf,
                                                const float* __restrict__ fc,
                                                const float* __restrict__ fs,
                                                u16* __restrict__ out) {
    const int t = blockIdx.x * 256 + threadIdx.x;     // 1048576 pairs
    const int row = t >> 8;                           // b*S+s
    const int w = t & 255;                            // kv*64+i
    const int kv = w >> 6, i = w & 63;
    const int b = row >> 11, s = row & 2047;
    const float2 p = ((const float2*)kf)[(size_t)row * 256 + w];
    const float c = fc[s * 64 + i], sn = fs[s * 64 + i];
    const float re = p.x * c - p.y * sn;
    const float im = p.x * sn + p.y * c;
    const unsigned val = (unsigned)f2bf(re) | ((unsigned)f2bf(im) << 16);
    ((unsigned*)out)[(((size_t)(b * NKV + kv) * SS + s) << 6) + i] = val;
}

// ---------------- V: fp32 [B*S][KV*D] -> bf16 [B][KV][D][S] (transposed) ----------------
__global__ __launch_bounds__(256) void k_vconv(const float* __restrict__ vf,
                                               u16* __restrict__ vt) {
    __shared__ float tile[32][33];
    const int bkv = blockIdx.x;
    const int st = blockIdx.y * 32, dt = blockIdx.z * 32;
    const int b = bkv >> 2, kv = bkv & 3;
    const int c = threadIdx.x & 31, r = threadIdx.x >> 5;
#pragma unroll
    for (int i = 0; i < 32; i += 8)
        tile[r + i][c] = vf[(size_t)(b * SS + st + r + i) * (NKV * DD) + kv * DD + dt + c];
    __syncthreads();
#pragma unroll
    for (int i = 0; i < 32; i += 8)
        vt[(size_t)(bkv * DD + dt + r + i) * SS + st + c] = f2bf(tile[c][r + i]);
}

// ---------------- flash attention ----------------
// grid (B*H, S/64). 4 waves, wave w owns q rows [qb+16w, qb+16w+16).
// K staged [32][128] swizzled; V staged [128][32] swizzled; P round-trips LDS (per-wave).
__global__ __launch_bounds__(256) void k_attn(const u16* __restrict__ Q,   // [B*H][S][D]
                                              const u16* __restrict__ K_,  // [B*KV][S][D]
                                              const u16* __restrict__ V_,  // [B*KV][D][S]
                                              u16* __restrict__ Ctx) {     // [B*S][H*D]
    __shared__ u16 Ks[32 * 128];
    __shared__ u16 Vs[128 * 32];
    __shared__ u16 Ps[4 * 16 * 32];

    const int tid = threadIdx.x;
    const int lane = tid & 63, wave = tid >> 6;
    const int bh = blockIdx.x;
    const int b = bh >> 4, h = bh & 15;
    const int kvh = (b << 2) | (h >> 2);
    const int qb = blockIdx.y * 64;
    const int r = lane & 15, q4 = lane >> 4;

    // Q A-frags (held in regs for the whole kernel)
    const u16* Qg = Q + ((size_t)bh * SS + qb + wave * 16 + r) * DD;
    short8 qfr[4];
#pragma unroll
    for (int c = 0; c < 4; c++) qfr[c] = *(const short8*)(Qg + c * 32 + q4 * 8);

    const u16* Kg = K_ + (size_t)kvh * SS * DD;
    const u16* Vg = V_ + (size_t)kvh * DD * SS;

    // staging maps
    const int krow = tid >> 4;                         // 0..15 (call0), +16 call1
    const int kchunk = (tid & 15) ^ (krow & 7);
    const int vd = tid >> 2;                           // 0..63 (call0), +64 call1
    const int vchunk = (tid & 3) ^ ((vd >> 1) & 3);

    float mrow[4] = {-1e30f, -1e30f, -1e30f, -1e30f};
    float lrow[4] = {0.f, 0.f, 0.f, 0.f};
    f32x4 oacc[8] = {};

    const int qmax = qb + wave * 16 + 15;
    const float scale = 0.08838834764831845f;          // 1/sqrt(128)

    for (int kb = 0; kb < qb + 64; kb += 32) {
        async_lds16(Kg + (size_t)(kb + krow) * DD + kchunk * 8,       Ks + wave * 512);
        async_lds16(Kg + (size_t)(kb + 16 + krow) * DD + kchunk * 8,  Ks + 2048 + wave * 512);
        async_lds16(Vg + (size_t)vd * SS + kb + vchunk * 8,           Vs + wave * 512);
        async_lds16(Vg + (size_t)(vd + 64) * SS + kb + vchunk * 8,    Vs + 2048 + wave * 512);
        __syncthreads();

        if (kb <= qmax) {                              // wave-uniform causal skip
            // S = Q K^T  (two 16x16 tiles covering 32 key positions)
            f32x4 sc[2] = {};
#pragma unroll
            for (int kt = 0; kt < 2; kt++) {
                const int kr = kt * 16 + r;
#pragma unroll
                for (int c = 0; c < 4; c++) {
                    short8 kf = *(const short8*)(Ks + kr * 128 + (((c * 4 + q4) ^ (kr & 7)) << 3));
                    sc[kt] = __builtin_amdgcn_mfma_f32_16x16x32_bf16(qfr[c], kf, sc[kt], 0, 0, 0);
                }
            }

            // online softmax (rows quad*4+g, 16 lanes of the quad hold the 16 cols)
            float alpha[4];
            u16* pb = Ps + wave * 512;
#pragma unroll
            for (int g = 0; g < 4; g++) {
                const int prow = q4 * 4 + g;
                const int qpos = qb + wave * 16 + prow;
                float s0 = sc[0][g] * scale;
                float s1 = sc[1][g] * scale;
                const bool ok0 = (kb + r) <= qpos;
                const bool ok1 = (kb + 16 + r) <= qpos;
                s0 = ok0 ? s0 : -1e30f;
                s1 = ok1 ? s1 : -1e30f;
                float t = fmaxf(s0, s1);
                t = fmaxf(t, __shfl_xor(t, 1));
                t = fmaxf(t, __shfl_xor(t, 2));
                t = fmaxf(t, __shfl_xor(t, 4));
                t = fmaxf(t, __shfl_xor(t, 8));
                const float mnew = fmaxf(mrow[g], t);
                float p0 = ok0 ? __expf(s0 - mnew) : 0.f;
                float p1 = ok1 ? __expf(s1 - mnew) : 0.f;
                float rs = p0 + p1;
                rs += __shfl_xor(rs, 1);
                rs += __shfl_xor(rs, 2);
                rs += __shfl_xor(rs, 4);
                rs += __shfl_xor(rs, 8);
                alpha[g] = __expf(mrow[g] - mnew);
                lrow[g] = lrow[g] * alpha[g] + rs;
                mrow[g] = mnew;
                // store P in A-operand layout (swizzled), bf16
                const int swp = (prow >> 1) & 3;
                u16* pr = pb + prow * 32;
                pr[(((r >> 3) ^ swp) << 3) | (r & 7)] = f2bf(p0);
                pr[((((r >> 3) + 2) ^ swp) << 3) | (r & 7)] = f2bf(p1);
            }
#pragma unroll
            for (int dt = 0; dt < 8; dt++) {
                oacc[dt][0] *= alpha[0];
                oacc[dt][1] *= alpha[1];
                oacc[dt][2] *= alpha[2];
                oacc[dt][3] *= alpha[3];
            }
            // O += P V  (in-wave LDS round trip; ds ops of a wave are ordered)
            short8 pf = *(const short8*)(pb + r * 32 + ((q4 ^ ((r >> 1) & 3)) << 3));
#pragma unroll
            for (int dt = 0; dt < 8; dt++) {
                const int vr = dt * 16 + r;
                short8 vfr = *(const short8*)(Vs + vr * 32 + ((q4 ^ ((vr >> 1) & 3)) << 3));
                oacc[dt] = __builtin_amdgcn_mfma_f32_16x16x32_bf16(pf, vfr, oacc[dt], 0, 0, 0);
            }
        }
        __syncthreads();
    }

    float inv[4];
#pragma unroll
    for (int g = 0; g < 4; g++) inv[g] = 1.f / lrow[g];
#pragma unroll
    for (int g = 0; g < 4; g++) {
        const int spos = qb + wave * 16 + q4 * 4 + g;
        u16* outp = Ctx + ((size_t)b * SS + spos) * (NH * DD) + h * DD + r;
#pragma unroll
        for (int dt = 0; dt < 8; dt++)
            outp[dt * 16] = f2bf(oacc[dt][g] * inv[g]);
    }
}

extern "C" void kernel_launch(void* const* d_in, const int* in_sizes, int n_in,
                              void* d_out, int out_size, void* d_ws, size_t ws_size,
                              hipStream_t stream) {
    const float* query = (const float*)d_in[0];
    const float* key   = (const float*)d_in[1];
    const float* value = (const float*)d_in[2];
    // d_in[3] = mask (unused: causal -10000 underflows to exact 0 after fp32 softmax)
    const float* fc    = (const float*)d_in[4];
    const float* fs    = (const float*)d_in[5];
    const float* Wq    = (const float*)d_in[6];
    const float* bq    = (const float*)d_in[7];
    const float* Wk    = (const float*)d_in[8];
    const float* bk    = (const float*)d_in[9];
    const float* Wv    = (const float*)d_in[10];
    const float* bv    = (const float*)d_in[11];
    const float* Wo    = (const float*)d_in[12];
    const float* bo    = (const float*)d_in[13];
    float* out = (float*)d_out;

    char* w = (char*)d_ws;
    u16*   qbf = (u16*)(w);                      // 16 MB  bf16 query [4096][2048]
    u16*   kbf = (u16*)(w + 16777216);           // 16 MB  bf16 key
    u16*   vbf = (u16*)(w + 33554432);           // 16 MB  bf16 value
    u16*   Wqt = (u16*)(w + 50331648);           //  8 MB  Wq^T bf16 [2048][2048]
    u16*   Wkt = (u16*)(w + 58720256);           //  2 MB  Wk^T bf16 [512][2048]
    u16*   Wvt = (u16*)(w + 60817408);           //  2 MB  Wv^T bf16
    u16*   Wot = (u16*)(w + 62914560);           //  8 MB  Wo^T bf16
    float* qf  = (float*)(w + 71303168);         // 32 MB  q proj fp32 [4096][2048]
    float* kf  = (float*)(w + 104857600);        //  8 MB  k proj fp32 [4096][512]
    float* vf  = (float*)(w + 113246208);        //  8 MB  v proj fp32
    u16*   qro = (u16*)(w + 121634816);          // 16 MB  roped q bf16 [B][H][S][D]
    u16*   kro = (u16*)(w + 138412032);          //  4 MB  roped k bf16 [B][KV][S][D]
    u16*   vtr = (u16*)(w + 142606336);          //  4 MB  v bf16 [B][KV][D][S]
    u16*   ctx = (u16*)(w + 146800640);          // 16 MB  ctx bf16 [4096][2048]  (end ~156 MB)

    k_convert<<<8192, 256, 0, stream>>>(query, qbf, 2097152);
    k_convert<<<8192, 256, 0, stream>>>(key,   kbf, 2097152);
    k_convert<<<8192, 256, 0, stream>>>(value, vbf, 2097152);
    k_transpose_w<<<dim3(64, 64), 256, 0, stream>>>(Wq, Wqt, 2048, 2048);
    k_transpose_w<<<dim3(16, 64), 256, 0, stream>>>(Wk, Wkt, 2048, 512);
    k_transpose_w<<<dim3(16, 64), 256, 0, stream>>>(Wv, Wvt, 2048, 512);
    k_transpose_w<<<dim3(64, 64), 256, 0, stream>>>(Wo, Wot, 2048, 2048);

    k_gemm_bt<<<dim3(16, 32), 256, 0, stream>>>(qbf, Wqt, bq, qf, 4096, 2048, 2048);
    k_gemm_bt<<<dim3(4, 32),  256, 0, stream>>>(kbf, Wkt, bk, kf, 4096, 512, 2048);
    k_gemm_bt<<<dim3(4, 32),  256, 0, stream>>>(vbf, Wvt, bv, vf, 4096, 512, 2048);

    k_rope_q<<<16384, 256, 0, stream>>>(qf, fc, fs, qro);
    k_rope_k<<<4096, 256, 0, stream>>>(kf, fc, fs, kro);
    k_vconv<<<dim3(8, 64, 4), 256, 0, stream>>>(vf, vtr);

    k_attn<<<dim3(32, 32), 256, 0, stream>>>(qro, kro, vtr, ctx);

    k_gemm_bt<<<dim3(16, 32), 256, 0, stream>>>(ctx, Wot, bo, out, 4096, 2048, 2048);
}

// Round 2
// 497.910 us; speedup vs baseline: 1.1649x; 1.1649x over previous
//
#include <hip/hip_runtime.h>
#include <stdint.h>

// Problem constants
#define BB 2
#define SS 2048
#define HID 2048
#define NH 16
#define DD 128
#define NKV 4

typedef unsigned short u16;
typedef __attribute__((ext_vector_type(8))) short short8;   // 8 x bf16 (4 VGPRs) MFMA A/B frag
typedef __attribute__((ext_vector_type(4))) float f32x4;    // MFMA C/D frag

#if __has_builtin(__builtin_amdgcn_exp2f)
#define EXP2(x) __builtin_amdgcn_exp2f(x)
#else
#define EXP2(x) exp2f(x)
#endif

__device__ __forceinline__ u16 f2bf(float x) {
    union { float f; unsigned u; } v; v.f = x;
    unsigned u = v.u;
    return (u16)((u + 0x7FFFu + ((u >> 16) & 1u)) >> 16);   // RNE
}

// async global->LDS, 16B per lane. lds ptr must be wave-uniform (HW adds lane*16).
__device__ __forceinline__ void async_lds16(const void* g, void* l) {
    __builtin_amdgcn_global_load_lds(
        (const __attribute__((address_space(1))) void*)(uintptr_t)g,
        (__attribute__((address_space(3))) void*)(uintptr_t)l,
        16, 0, 0);
}

// ---------------- elementwise fp32 -> bf16 (q,k,v fused in one launch) ----------------
__global__ __launch_bounds__(256) void k_convert3(const float* __restrict__ a,
                                                  const float* __restrict__ b,
                                                  const float* __restrict__ c,
                                                  u16* __restrict__ oa,
                                                  u16* __restrict__ ob,
                                                  u16* __restrict__ oc) {
    int bid = blockIdx.x;
    const float* in; u16* out;
    if (bid < 8192)       { in = a; out = oa; }
    else if (bid < 16384) { in = b; out = ob; bid -= 8192; }
    else                  { in = c; out = oc; bid -= 16384; }
    const int i = bid * 256 + threadIdx.x;
    float4 v = ((const float4*)in)[i];
    uint2 o;
    o.x = (unsigned)f2bf(v.x) | ((unsigned)f2bf(v.y) << 16);
    o.y = (unsigned)f2bf(v.z) | ((unsigned)f2bf(v.w) << 16);
    ((uint2*)out)[i] = o;
}

// ---------------- weight transpose+convert: src fp32 [K][N] -> dst bf16 [N][K] ----------------
__global__ __launch_bounds__(256) void k_transpose_w(const float* __restrict__ src,
                                                     u16* __restrict__ dst, int K, int N) {
    __shared__ float tile[32][33];
    const int n0 = blockIdx.x * 32, k0 = blockIdx.y * 32;
    const int c = threadIdx.x & 31, r = threadIdx.x >> 5;
#pragma unroll
    for (int i = 0; i < 32; i += 8)
        tile[r + i][c] = src[(size_t)(k0 + r + i) * N + n0 + c];
    __syncthreads();
#pragma unroll
    for (int i = 0; i < 32; i += 8)
        dst[(size_t)(n0 + r + i) * K + k0 + c] = f2bf(tile[c][r + i]);
}

// ---------------- bf16 GEMM: C[M][N] = A[M][K] * Bt[N][K]^T + bias ----------------
__global__ __launch_bounds__(256) void k_gemm_bt(const u16* __restrict__ A,
                                                 const u16* __restrict__ Bt,
                                                 const float* __restrict__ bias,
                                                 float* __restrict__ C,
                                                 int M, int N, int K) {
    __shared__ u16 As[128 * 32];
    __shared__ u16 Bs[128 * 32];

    const int tid = threadIdx.x;
    const int lane = tid & 63, wave = tid >> 6;
    const int bm = blockIdx.y * 128, bn = blockIdx.x * 128;

    const int srow = tid >> 2, spos = tid & 3;
    const int c0 = (spos ^ ((srow >> 1) & 3)) * 8;
    const u16* gA0 = A  + (size_t)(bm + srow) * K + c0;
    const u16* gA1 = A  + (size_t)(bm + 64 + srow) * K + c0;
    const u16* gB0 = Bt + (size_t)(bn + srow) * K + c0;
    const u16* gB1 = Bt + (size_t)(bn + 64 + srow) * K + c0;

    const int r = lane & 15, q4 = lane >> 4;
    const int wm = (wave & 1) * 64, wn = (wave >> 1) * 64;

    int aoff[4], boff[4];
#pragma unroll
    for (int i = 0; i < 4; i++) {
        const int ar = wm + i * 16 + r;
        aoff[i] = ar * 32 + ((q4 ^ ((ar >> 1) & 3)) << 3);
        const int br = wn + i * 16 + r;
        boff[i] = br * 32 + ((q4 ^ ((br >> 1) & 3)) << 3);
    }

    f32x4 acc[4][4] = {};

    for (int kb = 0; kb < K; kb += 32) {
        async_lds16(gA0, As + wave * 512);
        async_lds16(gA1, As + 2048 + wave * 512);
        async_lds16(gB0, Bs + wave * 512);
        async_lds16(gB1, Bs + 2048 + wave * 512);
        gA0 += 32; gA1 += 32; gB0 += 32; gB1 += 32;
        __syncthreads();

        short8 av[4], bv_[4];
#pragma unroll
        for (int i = 0; i < 4; i++) av[i] = *(const short8*)(As + aoff[i]);
#pragma unroll
        for (int j = 0; j < 4; j++) bv_[j] = *(const short8*)(Bs + boff[j]);
#pragma unroll
        for (int i = 0; i < 4; i++)
#pragma unroll
            for (int j = 0; j < 4; j++)
                acc[i][j] = __builtin_amdgcn_mfma_f32_16x16x32_bf16(av[i], bv_[j], acc[i][j], 0, 0, 0);
        __syncthreads();
    }

#pragma unroll
    for (int j = 0; j < 4; j++) {
        const int col = bn + wn + j * 16 + r;
        const float bb = bias[col];
#pragma unroll
        for (int i = 0; i < 4; i++) {
            const int row = bm + wm + i * 16 + q4 * 4;
#pragma unroll
            for (int g = 0; g < 4; g++)
                C[(size_t)(row + g) * N + col] = acc[i][j][g] + bb;
        }
    }
}

// ---------------- RoPE q: fp32 [B*S][H*D] -> bf16 [B][H][S][D], pre-scaled ----------------
// fold softmax scale 1/sqrt(D) AND log2(e) into Q so attention works in log2 domain.
__global__ __launch_bounds__(256) void k_rope_q(const float* __restrict__ qf,
                                                const float* __restrict__ fc,
                                                const float* __restrict__ fs,
                                                u16* __restrict__ out) {
    const float qsc = 0.08838834764831845f * 1.4426950408889634f;
    const int t = blockIdx.x * 256 + threadIdx.x;
    const int row = t >> 10;
    const int w = t & 1023;
    const int h = w >> 6, i = w & 63;
    const int b = row >> 11, s = row & 2047;
    const float2 p = ((const float2*)qf)[(size_t)row * 1024 + w];
    const float c = fc[s * 64 + i], sn = fs[s * 64 + i];
    const float re = (p.x * c - p.y * sn) * qsc;
    const float im = (p.x * sn + p.y * c) * qsc;
    const unsigned val = (unsigned)f2bf(re) | ((unsigned)f2bf(im) << 16);
    ((unsigned*)out)[(((size_t)(b * NH + h) * SS + s) << 6) + i] = val;
}

// ---------------- RoPE k: fp32 [B*S][KV*D] -> bf16 [B][KV][S][D] ----------------
__global__ __launch_bounds__(256) void k_rope_k(const float* __restrict__ kf,
                                                const float* __restrict__ fc,
                                                const float* __restrict__ fs,
                                                u16* __restrict__ out) {
    const int t = blockIdx.x * 256 + threadIdx.x;
    const int row = t >> 8;
    const int w = t & 255;
    const int kv = w >> 6, i = w & 63;
    const int b = row >> 11, s = row & 2047;
    const float2 p = ((const float2*)kf)[(size_t)row * 256 + w];
    const float c = fc[s * 64 + i], sn = fs[s * 64 + i];
    const float re = p.x * c - p.y * sn;
    const float im = p.x * sn + p.y * c;
    const unsigned val = (unsigned)f2bf(re) | ((unsigned)f2bf(im) << 16);
    ((unsigned*)out)[(((size_t)(b * NKV + kv) * SS + s) << 6) + i] = val;
}

// ---------------- V: fp32 [B*S][KV*D] -> bf16 [B][KV][D][S] (transposed) ----------------
__global__ __launch_bounds__(256) void k_vconv(const float* __restrict__ vf,
                                               u16* __restrict__ vt) {
    __shared__ float tile[32][33];
    const int bkv = blockIdx.x;
    const int st = blockIdx.y * 32, dt = blockIdx.z * 32;
    const int b = bkv >> 2, kv = bkv & 3;
    const int c = threadIdx.x & 31, r = threadIdx.x >> 5;
#pragma unroll
    for (int i = 0; i < 32; i += 8)
        tile[r + i][c] = vf[(size_t)(b * SS + st + r + i) * (NKV * DD) + kv * DD + dt + c];
    __syncthreads();
#pragma unroll
    for (int i = 0; i < 32; i += 8)
        vt[(size_t)(bkv * DD + dt + r + i) * SS + st + c] = f2bf(tile[c][r + i]);
}

// ---------------- flash attention, transposed scores ----------------
// grid (B*H, S/64), heavy q-blocks first. Wave w owns q rows [qb+16w, qb+16w+16).
// S^T = K*Q^T: C-layout col = q (lane&15), rows = keys (regs) -> softmax reductions in-lane.
// Q pre-scaled by 1/sqrt(D)*log2e -> exp2 softmax. l-sum via ones-row MFMA.
__global__ __launch_bounds__(256) void k_attn(const u16* __restrict__ Q,   // [B*H][S][D] (scaled)
                                              const u16* __restrict__ K_,  // [B*KV][S][D]
                                              const u16* __restrict__ V_,  // [B*KV][D][S]
                                              u16* __restrict__ Ctx) {     // [B*S][H*D]
    __shared__ u16 Ks[32 * 128];
    __shared__ u16 Vs[128 * 32];
    __shared__ u16 Pb[4 * 16 * 40];   // per-wave P^(q x 32keys), 80B row stride (16B-aligned)

    const int tid = threadIdx.x;
    const int lane = tid & 63, wave = tid >> 6;
    const int bh = blockIdx.x;
    const int b = bh >> 4, h = bh & 15;
    const int kvh = (b << 2) | (h >> 2);
    const int qb = (gridDim.y - 1 - blockIdx.y) * 64;   // heavy-first for causal balance
    const int qcol = lane & 15, q4 = lane >> 4;
    const int qw = qb + wave * 16;

    // Q B-frags (regs, whole kernel): B[n=q][k=d]
    const u16* Qg = Q + ((size_t)bh * SS + qw + qcol) * DD;
    short8 qfr[4];
#pragma unroll
    for (int c = 0; c < 4; c++) qfr[c] = *(const short8*)(Qg + c * 32 + q4 * 8);

    const u16* Kg = K_ + (size_t)kvh * SS * DD;
    const u16* Vg = V_ + (size_t)kvh * DD * SS;

    // staging maps
    const int krow = tid >> 4;
    const int kchunk = (tid & 15) ^ (krow & 7);
    const int vd = tid >> 2;
    const int vchunk = (tid & 3) ^ ((vd >> 1) & 3);

    float m2 = -1e30f;          // running max (log2 domain)
    f32x4 lacc = {};            // running sum via ones-MFMA (all 4 regs equal)
    f32x4 oacc[8] = {};         // O^T [d=dt*16+q4*4+g][q=qcol]

    const short8 ones = {0x3F80, 0x3F80, 0x3F80, 0x3F80, 0x3F80, 0x3F80, 0x3F80, 0x3F80};
    u16* pb = Pb + wave * 640;
    unsigned* pb32 = (unsigned*)pb;

    for (int kb = 0; kb < qb + 64; kb += 32) {
        async_lds16(Kg + (size_t)(kb + krow) * DD + kchunk * 8,       Ks + wave * 512);
        async_lds16(Kg + (size_t)(kb + 16 + krow) * DD + kchunk * 8,  Ks + 2048 + wave * 512);
        async_lds16(Vg + (size_t)vd * SS + kb + vchunk * 8,           Vs + wave * 512);
        async_lds16(Vg + (size_t)(vd + 64) * SS + kb + vchunk * 8,    Vs + 2048 + wave * 512);
        __syncthreads();

        if (kb <= qw + 15) {                           // wave-uniform causal skip
            // S^T = K Q^T : D[key][q], col=q
            f32x4 sc[2] = {};
#pragma unroll
            for (int kt = 0; kt < 2; kt++) {
                const int kr = kt * 16 + qcol;         // A-row = key (lane&15)
#pragma unroll
                for (int c = 0; c < 4; c++) {
                    short8 kf = *(const short8*)(Ks + kr * 128 + (((c * 4 + q4) ^ (kr & 7)) << 3));
                    sc[kt] = __builtin_amdgcn_mfma_f32_16x16x32_bf16(kf, qfr[c], sc[kt], 0, 0, 0);
                }
            }

            // causal mask only on diagonal iterations (wave-uniform branch)
            if (kb + 32 > qw) {
#pragma unroll
                for (int kt = 0; kt < 2; kt++)
#pragma unroll
                    for (int g = 0; g < 4; g++) {
                        const int key = kb + kt * 16 + q4 * 4 + g;
                        if (key > qw + qcol) sc[kt][g] = -1e30f;
                    }
            }

            // row max: in-lane over 8 regs + cross-group shfl(16,32)
            float t = fmaxf(fmaxf(fmaxf(sc[0][0], sc[0][1]), fmaxf(sc[0][2], sc[0][3])),
                            fmaxf(fmaxf(sc[1][0], sc[1][1]), fmaxf(sc[1][2], sc[1][3])));
            t = fmaxf(t, __shfl_xor(t, 16));
            t = fmaxf(t, __shfl_xor(t, 32));
            const float mnew = fmaxf(m2, t);
            if (__any(mnew > m2)) {                    // rescale only when max moved
                const float alpha = EXP2(m2 - mnew);
#pragma unroll
                for (int dt = 0; dt < 8; dt++) {
                    oacc[dt][0] *= alpha; oacc[dt][1] *= alpha;
                    oacc[dt][2] *= alpha; oacc[dt][3] *= alpha;
                }
                lacc[0] *= alpha; lacc[1] *= alpha; lacc[2] *= alpha; lacc[3] *= alpha;
                m2 = mnew;
            }

            // p = 2^(s - m), pack to bf16 pairs via v_perm (truncation)
            float p0 = EXP2(sc[0][0] - m2), p1 = EXP2(sc[0][1] - m2);
            float p2 = EXP2(sc[0][2] - m2), p3 = EXP2(sc[0][3] - m2);
            float p4 = EXP2(sc[1][0] - m2), p5 = EXP2(sc[1][1] - m2);
            float p6 = EXP2(sc[1][2] - m2), p7 = EXP2(sc[1][3] - m2);
            const unsigned sel = 0x07060302u;
            unsigned pk0 = __builtin_amdgcn_perm(__float_as_uint(p1), __float_as_uint(p0), sel);
            unsigned pk1 = __builtin_amdgcn_perm(__float_as_uint(p3), __float_as_uint(p2), sel);
            unsigned pk2 = __builtin_amdgcn_perm(__float_as_uint(p5), __float_as_uint(p4), sel);
            unsigned pk3 = __builtin_amdgcn_perm(__float_as_uint(p7), __float_as_uint(p6), sel);

            // store P[q][key] (row=q=qcol, keys tile0 at u32 2q4, tile1 at 8+2q4)
            *(uint2*)(pb32 + qcol * 20 + 2 * q4)     = make_uint2(pk0, pk1);
            *(uint2*)(pb32 + qcol * 20 + 8 + 2 * q4) = make_uint2(pk2, pk3);

            // B-frag read: keys 8*q4..8*q4+7 of row q  (in-wave DS ordering)
            short8 pf = *(const short8*)(pb + qcol * 40 + q4 * 8);

            lacc = __builtin_amdgcn_mfma_f32_16x16x32_bf16(ones, pf, lacc, 0, 0, 0);
#pragma unroll
            for (int dt = 0; dt < 8; dt++) {
                const int vr = dt * 16 + qcol;
                short8 vfr = *(const short8*)(Vs + vr * 32 + ((q4 ^ ((vr >> 1) & 3)) << 3));
                oacc[dt] = __builtin_amdgcn_mfma_f32_16x16x32_bf16(vfr, pf, oacc[dt], 0, 0, 0);
            }
        }
        __syncthreads();
    }

    const float inv = 1.0f / lacc[0];
    u16* outp = Ctx + ((size_t)b * SS + qw + qcol) * (NH * DD) + h * DD;
#pragma unroll
    for (int dt = 0; dt < 8; dt++) {
        unsigned lo = (unsigned)f2bf(oacc[dt][0] * inv) | ((unsigned)f2bf(oacc[dt][1] * inv) << 16);
        unsigned hi = (unsigned)f2bf(oacc[dt][2] * inv) | ((unsigned)f2bf(oacc[dt][3] * inv) << 16);
        *(uint2*)(outp + dt * 16 + q4 * 4) = make_uint2(lo, hi);
    }
}

extern "C" void kernel_launch(void* const* d_in, const int* in_sizes, int n_in,
                              void* d_out, int out_size, void* d_ws, size_t ws_size,
                              hipStream_t stream) {
    const float* query = (const float*)d_in[0];
    const float* key   = (const float*)d_in[1];
    const float* value = (const float*)d_in[2];
    const float* fc    = (const float*)d_in[4];
    const float* fs    = (const float*)d_in[5];
    const float* Wq    = (const float*)d_in[6];
    const float* bq    = (const float*)d_in[7];
    const float* Wk    = (const float*)d_in[8];
    const float* bk    = (const float*)d_in[9];
    const float* Wv    = (const float*)d_in[10];
    const float* bv    = (const float*)d_in[11];
    const float* Wo    = (const float*)d_in[12];
    const float* bo    = (const float*)d_in[13];
    float* out = (float*)d_out;

    char* w = (char*)d_ws;
    u16*   qbf = (u16*)(w);
    u16*   kbf = (u16*)(w + 16777216);
    u16*   vbf = (u16*)(w + 33554432);
    u16*   Wqt = (u16*)(w + 50331648);
    u16*   Wkt = (u16*)(w + 58720256);
    u16*   Wvt = (u16*)(w + 60817408);
    u16*   Wot = (u16*)(w + 62914560);
    float* qf  = (float*)(w + 71303168);
    float* kf  = (float*)(w + 104857600);
    float* vf  = (float*)(w + 113246208);
    u16*   qro = (u16*)(w + 121634816);
    u16*   kro = (u16*)(w + 138412032);
    u16*   vtr = (u16*)(w + 142606336);
    u16*   ctx = (u16*)(w + 146800640);

    k_convert3<<<24576, 256, 0, stream>>>(query, key, value, qbf, kbf, vbf);
    k_transpose_w<<<dim3(64, 64), 256, 0, stream>>>(Wq, Wqt, 2048, 2048);
    k_transpose_w<<<dim3(16, 64), 256, 0, stream>>>(Wk, Wkt, 2048, 512);
    k_transpose_w<<<dim3(16, 64), 256, 0, stream>>>(Wv, Wvt, 2048, 512);
    k_transpose_w<<<dim3(64, 64), 256, 0, stream>>>(Wo, Wot, 2048, 2048);

    k_gemm_bt<<<dim3(16, 32), 256, 0, stream>>>(qbf, Wqt, bq, qf, 4096, 2048, 2048);
    k_gemm_bt<<<dim3(4, 32),  256, 0, stream>>>(kbf, Wkt, bk, kf, 4096, 512, 2048);
    k_gemm_bt<<<dim3(4, 32),  256, 0, stream>>>(vbf, Wvt, bv, vf, 4096, 512, 2048);

    k_rope_q<<<16384, 256, 0, stream>>>(qf, fc, fs, qro);
    k_rope_k<<<4096, 256, 0, stream>>>(kf, fc, fs, kro);
    k_vconv<<<dim3(8, 64, 4), 256, 0, stream>>>(vf, vtr);

    k_attn<<<dim3(32, 32), 256, 0, stream>>>(qro, kro, vtr, ctx);

    k_gemm_bt<<<dim3(16, 32), 256, 0, stream>>>(ctx, Wot, bo, out, 4096, 2048, 2048);
}

// Round 3
// 447.167 us; speedup vs baseline: 1.2971x; 1.1135x over previous
//
#include <hip/hip_runtime.h>
#include <stdint.h>

// Problem constants
#define BB 2
#define SS 2048
#define HID 2048
#define NH 16
#define DD 128
#define NKV 4

typedef unsigned short u16;
typedef __attribute__((ext_vector_type(8))) short short8;   // 8 x bf16 (4 VGPRs) MFMA A/B frag
typedef __attribute__((ext_vector_type(4))) float f32x4;    // MFMA C/D frag

#if __has_builtin(__builtin_amdgcn_exp2f)
#define EXP2(x) __builtin_amdgcn_exp2f(x)
#else
#define EXP2(x) exp2f(x)
#endif

__device__ __forceinline__ u16 f2bf(float x) {
    union { float f; unsigned u; } v; v.f = x;
    unsigned u = v.u;
    return (u16)((u + 0x7FFFu + ((u >> 16) & 1u)) >> 16);   // RNE
}

// async global->LDS, 16B per lane. lds ptr must be wave-uniform (HW adds lane*16).
__device__ __forceinline__ void async_lds16(const void* g, void* l) {
    __builtin_amdgcn_global_load_lds(
        (const __attribute__((address_space(1))) void*)(uintptr_t)g,
        (__attribute__((address_space(3))) void*)(uintptr_t)l,
        16, 0, 0);
}

// ---------------- prep: fp32->bf16 converts (q,k,v) + all weight transposes, one launch ----------
// blocks [0,24576): convert; [24576,34816): 32x32 transpose tiles (Wq|Wk|Wv -> Wt, Wo -> Wot)
__global__ __launch_bounds__(256) void k_prep(const float* __restrict__ query,
                                              const float* __restrict__ key,
                                              const float* __restrict__ value,
                                              const float* __restrict__ Wq,
                                              const float* __restrict__ Wk,
                                              const float* __restrict__ Wv,
                                              const float* __restrict__ Wo,
                                              u16* __restrict__ qbf,
                                              u16* __restrict__ kbf,
                                              u16* __restrict__ vbf,
                                              u16* __restrict__ Wt,
                                              u16* __restrict__ Wot) {
    __shared__ float tile[32][33];
    int x = blockIdx.x;
    if (x < 24576) {
        const float* in; u16* out;
        if (x < 8192)       { in = query; out = qbf; }
        else if (x < 16384) { in = key;   out = kbf; x -= 8192; }
        else                { in = value; out = vbf; x -= 16384; }
        const int i = x * 256 + threadIdx.x;
        float4 v = ((const float4*)in)[i];
        uint2 o;
        o.x = (unsigned)f2bf(v.x) | ((unsigned)f2bf(v.y) << 16);
        o.y = (unsigned)f2bf(v.z) | ((unsigned)f2bf(v.w) << 16);
        ((uint2*)out)[i] = o;
        return;
    }
    const int v_ = x - 24576;            // 0..10239
    const int ty = v_ / 160;             // k-tile 0..63
    const int xt = v_ - ty * 160;        // n-tile 0..159
    const float* src; u16* dst; int N, n0;
    if (xt < 64)      { src = Wq; dst = Wt;                          N = 2048; n0 = xt * 32; }
    else if (xt < 80) { src = Wk; dst = Wt + (size_t)2048 * 2048;    N = 512;  n0 = (xt - 64) * 32; }
    else if (xt < 96) { src = Wv; dst = Wt + (size_t)2560 * 2048;    N = 512;  n0 = (xt - 80) * 32; }
    else              { src = Wo; dst = Wot;                         N = 2048; n0 = (xt - 96) * 32; }
    const int k0 = ty * 32;
    const int c = threadIdx.x & 31, r = threadIdx.x >> 5;
#pragma unroll
    for (int i = 0; i < 32; i += 8)
        tile[r + i][c] = src[(size_t)(k0 + r + i) * N + n0 + c];
    __syncthreads();
#pragma unroll
    for (int i = 0; i < 32; i += 8)
        dst[(size_t)(n0 + r + i) * 2048 + k0 + c] = f2bf(tile[c][r + i]);
}

// ---------------- fused QKV projection GEMM ----------------
// grid (24, 32). bn<16: Q-proj (A=qbf, RoPE+scale epilogue -> qro[B][H][S][D]);
// bn 16..19: K-proj (A=kbf, RoPE -> kro[B][KV][S][D]); bn 20..23: V-proj (A=vbf -> vtr[B][KV][D][S]).
__global__ __launch_bounds__(256) void k_gemm_qkv(const u16* __restrict__ qbf,
                                                  const u16* __restrict__ kbf,
                                                  const u16* __restrict__ vbf,
                                                  const u16* __restrict__ Wt,   // [3072][2048] bf16
                                                  const float* __restrict__ bq,
                                                  const float* __restrict__ bk,
                                                  const float* __restrict__ bv,
                                                  const float* __restrict__ fc,
                                                  const float* __restrict__ fs,
                                                  u16* __restrict__ qro,
                                                  u16* __restrict__ kro,
                                                  u16* __restrict__ vtr) {
    __shared__ u16 As[128 * 32];
    __shared__ u16 Bs[128 * 32];

    const int tid = threadIdx.x;
    const int lane = tid & 63, wave = tid >> 6;
    const int bn = blockIdx.x;
    const int bm = blockIdx.y * 128;
    const u16* A = (bn < 16) ? qbf : (bn < 20) ? kbf : vbf;

    const int srow = tid >> 2, spos = tid & 3;
    const int c0 = (spos ^ ((srow >> 1) & 3)) * 8;
    const u16* gA0 = A  + (size_t)(bm + srow) * 2048 + c0;
    const u16* gA1 = A  + (size_t)(bm + 64 + srow) * 2048 + c0;
    const u16* gB0 = Wt + (size_t)(bn * 128 + srow) * 2048 + c0;
    const u16* gB1 = Wt + (size_t)(bn * 128 + 64 + srow) * 2048 + c0;

    const int r = lane & 15, q4 = lane >> 4;
    const int wm = (wave & 1) * 64, wn = (wave >> 1) * 64;

    int aoff[4], boff[4];
#pragma unroll
    for (int i = 0; i < 4; i++) {
        const int ar = wm + i * 16 + r;
        aoff[i] = ar * 32 + ((q4 ^ ((ar >> 1) & 3)) << 3);
        const int br = wn + i * 16 + r;
        boff[i] = br * 32 + ((q4 ^ ((br >> 1) & 3)) << 3);
    }

    f32x4 acc[4][4] = {};

    for (int kb = 0; kb < 2048; kb += 32) {
        async_lds16(gA0, As + wave * 512);
        async_lds16(gA1, As + 2048 + wave * 512);
        async_lds16(gB0, Bs + wave * 512);
        async_lds16(gB1, Bs + 2048 + wave * 512);
        gA0 += 32; gA1 += 32; gB0 += 32; gB1 += 32;
        __syncthreads();

        short8 av[4], bv_[4];
#pragma unroll
        for (int i = 0; i < 4; i++) av[i] = *(const short8*)(As + aoff[i]);
#pragma unroll
        for (int j = 0; j < 4; j++) bv_[j] = *(const short8*)(Bs + boff[j]);
#pragma unroll
        for (int i = 0; i < 4; i++)
#pragma unroll
            for (int j = 0; j < 4; j++)
                acc[i][j] = __builtin_amdgcn_mfma_f32_16x16x32_bf16(av[i], bv_[j], acc[i][j], 0, 0, 0);
        __syncthreads();
    }

    // ---------------- fused epilogues ----------------
    if (bn < 20) {
        // RoPE path (Q or K). col pairing (even,odd) = adjacent lanes r.
        const bool isQ = (bn < 16);
        const float qsc = isQ ? 0.08838834764831845f * 1.4426950408889634f : 1.0f;
        const float* bias = isQ ? bq : bk;
        const int colbase = isQ ? 0 : -2048;
#pragma unroll
        for (int j = 0; j < 4; j++) {
            const int col = bn * 128 + wn + j * 16 + r + colbase;   // local col within Q or K block
            const int d = col & 127;
            const int head = col >> 7;                              // h (Q) or kv (K)
            const int ii = d >> 1;
            const float ssign = (d & 1) ? 1.0f : -1.0f;
            const float bb = bias[col];
            u16* base = isQ ? qro : kro;
            const int nheads = isQ ? NH : NKV;
#pragma unroll
            for (int i = 0; i < 4; i++) {
                const int row0 = bm + wm + i * 16 + q4 * 4;
#pragma unroll
                for (int g = 0; g < 4; g++) {
                    const int row = row0 + g;
                    const int s = row & 2047, b = row >> 11;
                    const float val = acc[i][j][g] + bb;
                    const float other = __shfl_xor(val, 1);
                    const float cc = fc[s * 64 + ii], sn = fs[s * 64 + ii];
                    const float o = (val * cc + other * (sn * ssign)) * qsc;
                    const float po = __shfl_xor(o, 1);
                    if (!(d & 1)) {
                        const unsigned w = (unsigned)f2bf(o) | ((unsigned)f2bf(po) << 16);
                        *(unsigned*)(base + (((size_t)(b * nheads + head) * SS + s) << 7) + d) = w;
                    }
                }
            }
        }
    } else {
        // V path: convert + transpose to vtr[B][KV][D][S]
#pragma unroll
        for (int j = 0; j < 4; j++) {
            const int col = bn * 128 + wn + j * 16 + r - 2560;
            const int d = col & 127, kv = col >> 7;
            const float bb = bv[col];
#pragma unroll
            for (int i = 0; i < 4; i++) {
                const int row0 = bm + wm + i * 16 + q4 * 4;
                const int s0 = row0 & 2047, b = row0 >> 11;
                uint2 o;
                o.x = (unsigned)f2bf(acc[i][j][0] + bb) | ((unsigned)f2bf(acc[i][j][1] + bb) << 16);
                o.y = (unsigned)f2bf(acc[i][j][2] + bb) | ((unsigned)f2bf(acc[i][j][3] + bb) << 16);
                *(uint2*)(vtr + ((size_t)(b * NKV + kv) * DD + d) * SS + s0) = o;
            }
        }
    }
}

// ---------------- bf16 GEMM (O-projection): C[M][N] = A[M][K]*Bt[N][K]^T + bias, fp32 out ------
__global__ __launch_bounds__(256) void k_gemm_bt(const u16* __restrict__ A,
                                                 const u16* __restrict__ Bt,
                                                 const float* __restrict__ bias,
                                                 float* __restrict__ C,
                                                 int M, int N, int K) {
    __shared__ u16 As[128 * 32];
    __shared__ u16 Bs[128 * 32];

    const int tid = threadIdx.x;
    const int lane = tid & 63, wave = tid >> 6;
    const int bm = blockIdx.y * 128, bn = blockIdx.x * 128;

    const int srow = tid >> 2, spos = tid & 3;
    const int c0 = (spos ^ ((srow >> 1) & 3)) * 8;
    const u16* gA0 = A  + (size_t)(bm + srow) * K + c0;
    const u16* gA1 = A  + (size_t)(bm + 64 + srow) * K + c0;
    const u16* gB0 = Bt + (size_t)(bn + srow) * K + c0;
    const u16* gB1 = Bt + (size_t)(bn + 64 + srow) * K + c0;

    const int r = lane & 15, q4 = lane >> 4;
    const int wm = (wave & 1) * 64, wn = (wave >> 1) * 64;

    int aoff[4], boff[4];
#pragma unroll
    for (int i = 0; i < 4; i++) {
        const int ar = wm + i * 16 + r;
        aoff[i] = ar * 32 + ((q4 ^ ((ar >> 1) & 3)) << 3);
        const int br = wn + i * 16 + r;
        boff[i] = br * 32 + ((q4 ^ ((br >> 1) & 3)) << 3);
    }

    f32x4 acc[4][4] = {};

    for (int kb = 0; kb < K; kb += 32) {
        async_lds16(gA0, As + wave * 512);
        async_lds16(gA1, As + 2048 + wave * 512);
        async_lds16(gB0, Bs + wave * 512);
        async_lds16(gB1, Bs + 2048 + wave * 512);
        gA0 += 32; gA1 += 32; gB0 += 32; gB1 += 32;
        __syncthreads();

        short8 av[4], bv_[4];
#pragma unroll
        for (int i = 0; i < 4; i++) av[i] = *(const short8*)(As + aoff[i]);
#pragma unroll
        for (int j = 0; j < 4; j++) bv_[j] = *(const short8*)(Bs + boff[j]);
#pragma unroll
        for (int i = 0; i < 4; i++)
#pragma unroll
            for (int j = 0; j < 4; j++)
                acc[i][j] = __builtin_amdgcn_mfma_f32_16x16x32_bf16(av[i], bv_[j], acc[i][j], 0, 0, 0);
        __syncthreads();
    }

#pragma unroll
    for (int j = 0; j < 4; j++) {
        const int col = bn + wn + j * 16 + r;
        const float bb = bias[col];
#pragma unroll
        for (int i = 0; i < 4; i++) {
            const int row = bm + wm + i * 16 + q4 * 4;
#pragma unroll
            for (int g = 0; g < 4; g++)
                C[(size_t)(row + g) * N + col] = acc[i][j][g] + bb;
        }
    }
}

// ---------------- flash attention: no-max 2^s softmax, 32 q-rows/wave ----------------
// grid (B*H=32, S/128=16), heavy q-blocks first. Wave w owns q rows [qb+32w, qb+32w+32).
// S^T = K*Q^T (col=q in lanes, keys in regs). Q pre-scaled by (1/sqrt(D))*log2e at RoPE.
// p = 2^s directly (scores bounded, fp32 exp2 safe; softmax invariant to the shift).
__global__ __launch_bounds__(256) void k_attn(const u16* __restrict__ Q,   // [B*H][S][D] (scaled)
                                              const u16* __restrict__ K_,  // [B*KV][S][D]
                                              const u16* __restrict__ V_,  // [B*KV][D][S]
                                              u16* __restrict__ Ctx) {     // [B*S][H*D]
    __shared__ u16 Ks[32 * 128];       // 8 KB
    __shared__ u16 Vs[128 * 32];       // 8 KB
    __shared__ u16 Pb[4 * 32 * 40];    // 10 KB, 80B row stride

    const int tid = threadIdx.x;
    const int lane = tid & 63, wave = tid >> 6;
    const int bh = blockIdx.x;
    const int b = bh >> 4, h = bh & 15;
    const int kvh = (b << 2) | (h >> 2);
    const int qb = (gridDim.y - 1 - blockIdx.y) * 128;   // heavy-first
    const int qcol = lane & 15, q4 = lane >> 4;
    const int qw = qb + wave * 32;

    // Q B-frags for rows qw+qcol (qi=0) and qw+16+qcol (qi=1)
    const u16* Qg = Q + ((size_t)bh * SS + qw + qcol) * DD;
    short8 qfr[2][4];
#pragma unroll
    for (int qi = 0; qi < 2; qi++)
#pragma unroll
        for (int c = 0; c < 4; c++)
            qfr[qi][c] = *(const short8*)(Qg + qi * 16 * DD + c * 32 + q4 * 8);

    const u16* Kg = K_ + (size_t)kvh * SS * DD;
    const u16* Vg = V_ + (size_t)kvh * DD * SS;

    const int krow = tid >> 4;
    const int kchunk = (tid & 15) ^ (krow & 7);
    const int vd = tid >> 2;
    const int vchunk = (tid & 3) ^ ((vd >> 1) & 3);

    f32x4 lacc[2] = {};
    f32x4 oacc[2][8] = {};

    const short8 ones = {0x3F80, 0x3F80, 0x3F80, 0x3F80, 0x3F80, 0x3F80, 0x3F80, 0x3F80};
    u16* pb = Pb + wave * 1280;
    unsigned* pb32 = (unsigned*)pb;

    for (int kb = 0; kb < qb + 128; kb += 32) {
        async_lds16(Kg + (size_t)(kb + krow) * DD + kchunk * 8,       Ks + wave * 512);
        async_lds16(Kg + (size_t)(kb + 16 + krow) * DD + kchunk * 8,  Ks + 2048 + wave * 512);
        async_lds16(Vg + (size_t)vd * SS + kb + vchunk * 8,           Vs + wave * 512);
        async_lds16(Vg + (size_t)(vd + 64) * SS + kb + vchunk * 8,    Vs + 2048 + wave * 512);
        __syncthreads();

        if (kb <= qw + 31) {                           // wave-uniform causal skip
            f32x4 sc[2][2] = {};
#pragma unroll
            for (int kt = 0; kt < 2; kt++) {
                const int kr = kt * 16 + qcol;
#pragma unroll
                for (int c = 0; c < 4; c++) {
                    short8 kf = *(const short8*)(Ks + kr * 128 + (((c * 4 + q4) ^ (kr & 7)) << 3));
                    sc[kt][0] = __builtin_amdgcn_mfma_f32_16x16x32_bf16(kf, qfr[0][c], sc[kt][0], 0, 0, 0);
                    sc[kt][1] = __builtin_amdgcn_mfma_f32_16x16x32_bf16(kf, qfr[1][c], sc[kt][1], 0, 0, 0);
                }
            }

            if (kb + 32 > qw) {                        // single diagonal tile per wave
#pragma unroll
                for (int kt = 0; kt < 2; kt++)
#pragma unroll
                    for (int qi = 0; qi < 2; qi++)
#pragma unroll
                        for (int g = 0; g < 4; g++) {
                            const int key = kb + kt * 16 + q4 * 4 + g;
                            if (key > qw + qi * 16 + qcol) sc[kt][qi][g] = -1e30f;
                        }
            }

            const unsigned sel = 0x07060302u;
#pragma unroll
            for (int qi = 0; qi < 2; qi++) {
                float p0 = EXP2(sc[0][qi][0]), p1 = EXP2(sc[0][qi][1]);
                float p2 = EXP2(sc[0][qi][2]), p3 = EXP2(sc[0][qi][3]);
                float p4 = EXP2(sc[1][qi][0]), p5 = EXP2(sc[1][qi][1]);
                float p6 = EXP2(sc[1][qi][2]), p7 = EXP2(sc[1][qi][3]);
                unsigned pk0 = __builtin_amdgcn_perm(__float_as_uint(p1), __float_as_uint(p0), sel);
                unsigned pk1 = __builtin_amdgcn_perm(__float_as_uint(p3), __float_as_uint(p2), sel);
                unsigned pk2 = __builtin_amdgcn_perm(__float_as_uint(p5), __float_as_uint(p4), sel);
                unsigned pk3 = __builtin_amdgcn_perm(__float_as_uint(p7), __float_as_uint(p6), sel);
                const int row = qi * 16 + qcol;
                *(uint2*)(pb32 + row * 20 + 2 * q4)     = make_uint2(pk0, pk1);
                *(uint2*)(pb32 + row * 20 + 8 + 2 * q4) = make_uint2(pk2, pk3);
            }

            short8 pf0 = *(const short8*)(pb + qcol * 40 + q4 * 8);
            short8 pf1 = *(const short8*)(pb + (16 + qcol) * 40 + q4 * 8);

            lacc[0] = __builtin_amdgcn_mfma_f32_16x16x32_bf16(ones, pf0, lacc[0], 0, 0, 0);
            lacc[1] = __builtin_amdgcn_mfma_f32_16x16x32_bf16(ones, pf1, lacc[1], 0, 0, 0);
#pragma unroll
            for (int dt = 0; dt < 8; dt++) {
                const int vr = dt * 16 + qcol;
                short8 vfr = *(const short8*)(Vs + vr * 32 + ((q4 ^ ((vr >> 1) & 3)) << 3));
                oacc[0][dt] = __builtin_amdgcn_mfma_f32_16x16x32_bf16(vfr, pf0, oacc[0][dt], 0, 0, 0);
                oacc[1][dt] = __builtin_amdgcn_mfma_f32_16x16x32_bf16(vfr, pf1, oacc[1][dt], 0, 0, 0);
            }
        }
        __syncthreads();
    }

#pragma unroll
    for (int qi = 0; qi < 2; qi++) {
        const float inv = 1.0f / lacc[qi][0];
        u16* outp = Ctx + ((size_t)b * SS + qw + qi * 16 + qcol) * (NH * DD) + h * DD;
#pragma unroll
        for (int dt = 0; dt < 8; dt++) {
            unsigned lo = (unsigned)f2bf(oacc[qi][dt][0] * inv) | ((unsigned)f2bf(oacc[qi][dt][1] * inv) << 16);
            unsigned hi = (unsigned)f2bf(oacc[qi][dt][2] * inv) | ((unsigned)f2bf(oacc[qi][dt][3] * inv) << 16);
            *(uint2*)(outp + dt * 16 + q4 * 4) = make_uint2(lo, hi);
        }
    }
}

extern "C" void kernel_launch(void* const* d_in, const int* in_sizes, int n_in,
                              void* d_out, int out_size, void* d_ws, size_t ws_size,
                              hipStream_t stream) {
    const float* query = (const float*)d_in[0];
    const float* key   = (const float*)d_in[1];
    const float* value = (const float*)d_in[2];
    const float* fc    = (const float*)d_in[4];
    const float* fs    = (const float*)d_in[5];
    const float* Wq    = (const float*)d_in[6];
    const float* bq    = (const float*)d_in[7];
    const float* Wk    = (const float*)d_in[8];
    const float* bk    = (const float*)d_in[9];
    const float* Wv    = (const float*)d_in[10];
    const float* bv    = (const float*)d_in[11];
    const float* Wo    = (const float*)d_in[12];
    const float* bo    = (const float*)d_in[13];
    float* out = (float*)d_out;

    char* w = (char*)d_ws;
    u16* qbf = (u16*)(w);                    // 16 MB  bf16 query [4096][2048]
    u16* kbf = (u16*)(w + 16777216);         // 16 MB
    u16* vbf = (u16*)(w + 33554432);         // 16 MB
    u16* Wt  = (u16*)(w + 50331648);         // 12 MB  [Wq|Wk|Wv]^T bf16 [3072][2048]
    u16* Wot = (u16*)(w + 62914560);         //  8 MB  Wo^T bf16 [2048][2048]
    u16* qro = (u16*)(w + 71303168);         // 16 MB  roped+scaled q bf16 [B][H][S][D]
    u16* kro = (u16*)(w + 88080384);         //  4 MB  roped k bf16 [B][KV][S][D]
    u16* vtr = (u16*)(w + 92274688);         //  4 MB  v bf16 [B][KV][D][S]
    u16* ctx = (u16*)(w + 96468992);         // 16 MB  ctx bf16 [4096][2048]  (end 108 MB)

    k_prep<<<34816, 256, 0, stream>>>(query, key, value, Wq, Wk, Wv, Wo,
                                      qbf, kbf, vbf, Wt, Wot);
    k_gemm_qkv<<<dim3(24, 32), 256, 0, stream>>>(qbf, kbf, vbf, Wt, bq, bk, bv,
                                                 fc, fs, qro, kro, vtr);
    k_attn<<<dim3(32, 16), 256, 0, stream>>>(qro, kro, vtr, ctx);
    k_gemm_bt<<<dim3(16, 32), 256, 0, stream>>>(ctx, Wot, bo, out, 4096, 2048, 2048);
}

// Round 4
// 421.107 us; speedup vs baseline: 1.3773x; 1.0619x over previous
//
#include <hip/hip_runtime.h>
#include <stdint.h>

// Problem constants
#define BB 2
#define SS 2048
#define HID 2048
#define NH 16
#define DD 128
#define NKV 4

typedef unsigned short u16;
typedef __attribute__((ext_vector_type(8))) short short8;   // 8 x bf16 (4 VGPRs) MFMA A/B frag
typedef __attribute__((ext_vector_type(4))) float f32x4;    // MFMA C/D frag

#if __has_builtin(__builtin_amdgcn_exp2f)
#define EXP2(x) __builtin_amdgcn_exp2f(x)
#else
#define EXP2(x) exp2f(x)
#endif

__device__ __forceinline__ u16 f2bf(float x) {
    union { float f; unsigned u; } v; v.f = x;
    unsigned u = v.u;
    return (u16)((u + 0x7FFFu + ((u >> 16) & 1u)) >> 16);   // RNE
}

// async global->LDS, 16B per lane. lds ptr must be wave-uniform (HW adds lane*16).
__device__ __forceinline__ void async_lds16(const void* g, void* l) {
    __builtin_amdgcn_global_load_lds(
        (const __attribute__((address_space(1))) void*)(uintptr_t)g,
        (__attribute__((address_space(3))) void*)(uintptr_t)l,
        16, 0, 0);
}

// ---------------- prep: fp32->bf16 converts (q,k,v) + all weight transposes, one launch ----------
__global__ __launch_bounds__(256) void k_prep(const float* __restrict__ query,
                                              const float* __restrict__ key,
                                              const float* __restrict__ value,
                                              const float* __restrict__ Wq,
                                              const float* __restrict__ Wk,
                                              const float* __restrict__ Wv,
                                              const float* __restrict__ Wo,
                                              u16* __restrict__ qbf,
                                              u16* __restrict__ kbf,
                                              u16* __restrict__ vbf,
                                              u16* __restrict__ Wt,
                                              u16* __restrict__ Wot) {
    __shared__ float tile[32][33];
    int x = blockIdx.x;
    if (x < 24576) {
        const float* in; u16* out;
        if (x < 8192)       { in = query; out = qbf; }
        else if (x < 16384) { in = key;   out = kbf; x -= 8192; }
        else                { in = value; out = vbf; x -= 16384; }
        const int i = x * 256 + threadIdx.x;
        float4 v = ((const float4*)in)[i];
        uint2 o;
        o.x = (unsigned)f2bf(v.x) | ((unsigned)f2bf(v.y) << 16);
        o.y = (unsigned)f2bf(v.z) | ((unsigned)f2bf(v.w) << 16);
        ((uint2*)out)[i] = o;
        return;
    }
    const int v_ = x - 24576;            // 0..10239
    const int ty = v_ / 160;             // k-tile 0..63
    const int xt = v_ - ty * 160;        // n-tile 0..159
    const float* src; u16* dst; int N, n0;
    if (xt < 64)      { src = Wq; dst = Wt;                          N = 2048; n0 = xt * 32; }
    else if (xt < 80) { src = Wk; dst = Wt + (size_t)2048 * 2048;    N = 512;  n0 = (xt - 64) * 32; }
    else if (xt < 96) { src = Wv; dst = Wt + (size_t)2560 * 2048;    N = 512;  n0 = (xt - 80) * 32; }
    else              { src = Wo; dst = Wot;                         N = 2048; n0 = (xt - 96) * 32; }
    const int k0 = ty * 32;
    const int c = threadIdx.x & 31, r = threadIdx.x >> 5;
#pragma unroll
    for (int i = 0; i < 32; i += 8)
        tile[r + i][c] = src[(size_t)(k0 + r + i) * N + n0 + c];
    __syncthreads();
#pragma unroll
    for (int i = 0; i < 32; i += 8)
        dst[(size_t)(n0 + r + i) * 2048 + k0 + c] = f2bf(tile[c][r + i]);
}

// ---------------- fused QKV projection GEMM ----------------
// grid (24, 32). bn<16: Q-proj (RoPE+scale -> qro[B][H][S][D]); bn 16..19: K-proj (RoPE ->
// kro[B][KV][S][D]); bn 20..23: V-proj (-> vtr[B][KV][D][S]).
// RoPE epilogue: per-wave LDS transpose (row stride 20 words: 2-way on write = free) so each
// lane owns one s-row -> fc/fs are float4 loads, pair-mix in-lane, one uint4 store per pass.
__global__ __launch_bounds__(256) void k_gemm_qkv(const u16* __restrict__ qbf,
                                                  const u16* __restrict__ kbf,
                                                  const u16* __restrict__ vbf,
                                                  const u16* __restrict__ Wt,   // [3072][2048] bf16
                                                  const float* __restrict__ bq,
                                                  const float* __restrict__ bk,
                                                  const float* __restrict__ bv,
                                                  const float* __restrict__ fc,
                                                  const float* __restrict__ fs,
                                                  u16* __restrict__ qro,
                                                  u16* __restrict__ kro,
                                                  u16* __restrict__ vtr) {
    __shared__ u16 As[128 * 32];
    __shared__ u16 Bs[128 * 32];
    __shared__ float Ep[4 * 64 * 20];     // 20 KB: per-wave 64x16 fp32 transpose scratch

    const int tid = threadIdx.x;
    const int lane = tid & 63, wave = tid >> 6;
    const int bn = blockIdx.x;
    const int bm = blockIdx.y * 128;
    const u16* A = (bn < 16) ? qbf : (bn < 20) ? kbf : vbf;

    const int srow = tid >> 2, spos = tid & 3;
    const int c0 = (spos ^ ((srow >> 1) & 3)) * 8;
    const u16* gA0 = A  + (size_t)(bm + srow) * 2048 + c0;
    const u16* gA1 = A  + (size_t)(bm + 64 + srow) * 2048 + c0;
    const u16* gB0 = Wt + (size_t)(bn * 128 + srow) * 2048 + c0;
    const u16* gB1 = Wt + (size_t)(bn * 128 + 64 + srow) * 2048 + c0;

    const int r = lane & 15, q4 = lane >> 4;
    const int wm = (wave & 1) * 64, wn = (wave >> 1) * 64;

    int aoff[4], boff[4];
#pragma unroll
    for (int i = 0; i < 4; i++) {
        const int ar = wm + i * 16 + r;
        aoff[i] = ar * 32 + ((q4 ^ ((ar >> 1) & 3)) << 3);
        const int br = wn + i * 16 + r;
        boff[i] = br * 32 + ((q4 ^ ((br >> 1) & 3)) << 3);
    }

    f32x4 acc[4][4] = {};

    for (int kb = 0; kb < 2048; kb += 32) {
        async_lds16(gA0, As + wave * 512);
        async_lds16(gA1, As + 2048 + wave * 512);
        async_lds16(gB0, Bs + wave * 512);
        async_lds16(gB1, Bs + 2048 + wave * 512);
        gA0 += 32; gA1 += 32; gB0 += 32; gB1 += 32;
        __syncthreads();

        short8 av[4], bv_[4];
#pragma unroll
        for (int i = 0; i < 4; i++) av[i] = *(const short8*)(As + aoff[i]);
#pragma unroll
        for (int j = 0; j < 4; j++) bv_[j] = *(const short8*)(Bs + boff[j]);
#pragma unroll
        for (int i = 0; i < 4; i++)
#pragma unroll
            for (int j = 0; j < 4; j++)
                acc[i][j] = __builtin_amdgcn_mfma_f32_16x16x32_bf16(av[i], bv_[j], acc[i][j], 0, 0, 0);
        __syncthreads();
    }

    // ---------------- fused epilogues ----------------
    if (bn < 20) {
        const bool isQ = (bn < 16);
        const float qsc = isQ ? 0.08838834764831845f * 1.4426950408889634f : 1.0f;
        const float* bias = isQ ? bq : bk;
        const int head = isQ ? bn : (bn - 16);
        u16* base = isQ ? qro : kro;
        const int nheads = isQ ? NH : NKV;

        float* ep = Ep + wave * 1280;           // 64 rows x 20 words
        const int rowg = bm + wm + lane;        // this lane's s-row (read phase)
        const int s = rowg & 2047, bidx = rowg >> 11;
        const float* fcp0 = fc + s * 64;
        const float* fsp0 = fs + s * 64;

#pragma unroll
        for (int j = 0; j < 4; j++) {
            const float bcol = bias[head * 128 + wn + j * 16 + r];
            // write phase: (row = wave-local M index, col = r), in-wave DS ordering
#pragma unroll
            for (int i = 0; i < 4; i++)
#pragma unroll
                for (int g = 0; g < 4; g++)
                    ep[(i * 16 + q4 * 4 + g) * 20 + r] = acc[i][j][g] + bcol;
            // read phase: lane owns row `lane`, 16 consecutive cols
            float4 x0 = *(float4*)(ep + lane * 20 + 0);
            float4 x1 = *(float4*)(ep + lane * 20 + 4);
            float4 x2 = *(float4*)(ep + lane * 20 + 8);
            float4 x3 = *(float4*)(ep + lane * 20 + 12);
            const int d0 = wn + j * 16;
            const int ii0 = d0 >> 1;
            float4 ca = *(const float4*)(fcp0 + ii0);
            float4 cb = *(const float4*)(fcp0 + ii0 + 4);
            float4 sa = *(const float4*)(fsp0 + ii0);
            float4 sb = *(const float4*)(fsp0 + ii0 + 4);
            float o[16];
            o[0]  = (x0.x * ca.x - x0.y * sa.x) * qsc;  o[1]  = (x0.x * sa.x + x0.y * ca.x) * qsc;
            o[2]  = (x0.z * ca.y - x0.w * sa.y) * qsc;  o[3]  = (x0.z * sa.y + x0.w * ca.y) * qsc;
            o[4]  = (x1.x * ca.z - x1.y * sa.z) * qsc;  o[5]  = (x1.x * sa.z + x1.y * ca.z) * qsc;
            o[6]  = (x1.z * ca.w - x1.w * sa.w) * qsc;  o[7]  = (x1.z * sa.w + x1.w * ca.w) * qsc;
            o[8]  = (x2.x * cb.x - x2.y * sb.x) * qsc;  o[9]  = (x2.x * sb.x + x2.y * cb.x) * qsc;
            o[10] = (x2.z * cb.y - x2.w * sb.y) * qsc;  o[11] = (x2.z * sb.y + x2.w * cb.y) * qsc;
            o[12] = (x3.x * cb.z - x3.y * sb.z) * qsc;  o[13] = (x3.x * sb.z + x3.y * cb.z) * qsc;
            o[14] = (x3.z * cb.w - x3.w * sb.w) * qsc;  o[15] = (x3.z * sb.w + x3.w * cb.w) * qsc;
            uint4 pk;
            pk.x = (unsigned)f2bf(o[0])  | ((unsigned)f2bf(o[1])  << 16) ;
            pk.x |= 0u; // keep simple
            pk.x = (unsigned)f2bf(o[0])  | ((unsigned)f2bf(o[1])  << 16);
            unsigned w1 = (unsigned)f2bf(o[2])  | ((unsigned)f2bf(o[3])  << 16);
            unsigned w2 = (unsigned)f2bf(o[4])  | ((unsigned)f2bf(o[5])  << 16);
            unsigned w3 = (unsigned)f2bf(o[6])  | ((unsigned)f2bf(o[7])  << 16);
            unsigned w4 = (unsigned)f2bf(o[8])  | ((unsigned)f2bf(o[9])  << 16);
            unsigned w5 = (unsigned)f2bf(o[10]) | ((unsigned)f2bf(o[11]) << 16);
            unsigned w6 = (unsigned)f2bf(o[12]) | ((unsigned)f2bf(o[13]) << 16);
            unsigned w7 = (unsigned)f2bf(o[14]) | ((unsigned)f2bf(o[15]) << 16);
            uint4 lo_ = make_uint4(pk.x, w1, w2, w3);
            uint4 hi_ = make_uint4(w4, w5, w6, w7);
            u16* dst = base + (((size_t)(bidx * nheads + head) * SS + s) << 7) + d0;
            *(uint4*)dst = lo_;
            *(uint4*)(dst + 8) = hi_;
        }
    } else {
        // V path: convert + transpose to vtr[B][KV][D][S]
#pragma unroll
        for (int j = 0; j < 4; j++) {
            const int col = bn * 128 + wn + j * 16 + r - 2560;
            const int d = col & 127, kv = col >> 7;
            const float bb = bv[col];
#pragma unroll
            for (int i = 0; i < 4; i++) {
                const int row0 = bm + wm + i * 16 + q4 * 4;
                const int s0 = row0 & 2047, b = row0 >> 11;
                uint2 o;
                o.x = (unsigned)f2bf(acc[i][j][0] + bb) | ((unsigned)f2bf(acc[i][j][1] + bb) << 16);
                o.y = (unsigned)f2bf(acc[i][j][2] + bb) | ((unsigned)f2bf(acc[i][j][3] + bb) << 16);
                *(uint2*)(vtr + ((size_t)(b * NKV + kv) * DD + d) * SS + s0) = o;
            }
        }
    }
}

// ---------------- bf16 GEMM (O-projection): C[M][N] = A[M][K]*Bt[N][K]^T + bias, fp32 out ------
__global__ __launch_bounds__(256) void k_gemm_bt(const u16* __restrict__ A,
                                                 const u16* __restrict__ Bt,
                                                 const float* __restrict__ bias,
                                                 float* __restrict__ C,
                                                 int M, int N, int K) {
    __shared__ u16 As[128 * 32];
    __shared__ u16 Bs[128 * 32];

    const int tid = threadIdx.x;
    const int lane = tid & 63, wave = tid >> 6;
    const int bm = blockIdx.y * 128, bn = blockIdx.x * 128;

    const int srow = tid >> 2, spos = tid & 3;
    const int c0 = (spos ^ ((srow >> 1) & 3)) * 8;
    const u16* gA0 = A  + (size_t)(bm + srow) * K + c0;
    const u16* gA1 = A  + (size_t)(bm + 64 + srow) * K + c0;
    const u16* gB0 = Bt + (size_t)(bn + srow) * K + c0;
    const u16* gB1 = Bt + (size_t)(bn + 64 + srow) * K + c0;

    const int r = lane & 15, q4 = lane >> 4;
    const int wm = (wave & 1) * 64, wn = (wave >> 1) * 64;

    int aoff[4], boff[4];
#pragma unroll
    for (int i = 0; i < 4; i++) {
        const int ar = wm + i * 16 + r;
        aoff[i] = ar * 32 + ((q4 ^ ((ar >> 1) & 3)) << 3);
        const int br = wn + i * 16 + r;
        boff[i] = br * 32 + ((q4 ^ ((br >> 1) & 3)) << 3);
    }

    f32x4 acc[4][4] = {};

    for (int kb = 0; kb < K; kb += 32) {
        async_lds16(gA0, As + wave * 512);
        async_lds16(gA1, As + 2048 + wave * 512);
        async_lds16(gB0, Bs + wave * 512);
        async_lds16(gB1, Bs + 2048 + wave * 512);
        gA0 += 32; gA1 += 32; gB0 += 32; gB1 += 32;
        __syncthreads();

        short8 av[4], bv_[4];
#pragma unroll
        for (int i = 0; i < 4; i++) av[i] = *(const short8*)(As + aoff[i]);
#pragma unroll
        for (int j = 0; j < 4; j++) bv_[j] = *(const short8*)(Bs + boff[j]);
#pragma unroll
        for (int i = 0; i < 4; i++)
#pragma unroll
            for (int j = 0; j < 4; j++)
                acc[i][j] = __builtin_amdgcn_mfma_f32_16x16x32_bf16(av[i], bv_[j], acc[i][j], 0, 0, 0);
        __syncthreads();
    }

#pragma unroll
    for (int j = 0; j < 4; j++) {
        const int col = bn + wn + j * 16 + r;
        const float bb = bias[col];
#pragma unroll
        for (int i = 0; i < 4; i++) {
            const int row = bm + wm + i * 16 + q4 * 4;
#pragma unroll
            for (int g = 0; g < 4; g++)
                C[(size_t)(row + g) * N + col] = acc[i][j][g] + bb;
        }
    }
}

// ---------------- flash attention: no-max 2^s softmax, 32 q-rows/wave ----------------
__global__ __launch_bounds__(256) void k_attn(const u16* __restrict__ Q,   // [B*H][S][D] (scaled)
                                              const u16* __restrict__ K_,  // [B*KV][S][D]
                                              const u16* __restrict__ V_,  // [B*KV][D][S]
                                              u16* __restrict__ Ctx) {     // [B*S][H*D]
    __shared__ u16 Ks[32 * 128];       // 8 KB
    __shared__ u16 Vs[128 * 32];       // 8 KB
    __shared__ u16 Pb[4 * 32 * 40];    // 10 KB, 80B row stride

    const int tid = threadIdx.x;
    const int lane = tid & 63, wave = tid >> 6;
    const int bh = blockIdx.x;
    const int b = bh >> 4, h = bh & 15;
    const int kvh = (b << 2) | (h >> 2);
    const int qb = (gridDim.y - 1 - blockIdx.y) * 128;   // heavy-first
    const int qcol = lane & 15, q4 = lane >> 4;
    const int qw = qb + wave * 32;

    const u16* Qg = Q + ((size_t)bh * SS + qw + qcol) * DD;
    short8 qfr[2][4];
#pragma unroll
    for (int qi = 0; qi < 2; qi++)
#pragma unroll
        for (int c = 0; c < 4; c++)
            qfr[qi][c] = *(const short8*)(Qg + qi * 16 * DD + c * 32 + q4 * 8);

    const u16* Kg = K_ + (size_t)kvh * SS * DD;
    const u16* Vg = V_ + (size_t)kvh * DD * SS;

    const int krow = tid >> 4;
    const int kchunk = (tid & 15) ^ (krow & 7);
    const int vd = tid >> 2;
    const int vchunk = (tid & 3) ^ ((vd >> 1) & 3);

    f32x4 lacc[2] = {};
    f32x4 oacc[2][8] = {};

    const short8 ones = {0x3F80, 0x3F80, 0x3F80, 0x3F80, 0x3F80, 0x3F80, 0x3F80, 0x3F80};
    u16* pb = Pb + wave * 1280;
    unsigned* pb32 = (unsigned*)pb;

    for (int kb = 0; kb < qb + 128; kb += 32) {
        async_lds16(Kg + (size_t)(kb + krow) * DD + kchunk * 8,       Ks + wave * 512);
        async_lds16(Kg + (size_t)(kb + 16 + krow) * DD + kchunk * 8,  Ks + 2048 + wave * 512);
        async_lds16(Vg + (size_t)vd * SS + kb + vchunk * 8,           Vs + wave * 512);
        async_lds16(Vg + (size_t)(vd + 64) * SS + kb + vchunk * 8,    Vs + 2048 + wave * 512);
        __syncthreads();

        if (kb <= qw + 31) {                           // wave-uniform causal skip
            f32x4 sc[2][2] = {};
#pragma unroll
            for (int kt = 0; kt < 2; kt++) {
                const int kr = kt * 16 + qcol;
#pragma unroll
                for (int c = 0; c < 4; c++) {
                    short8 kf = *(const short8*)(Ks + kr * 128 + (((c * 4 + q4) ^ (kr & 7)) << 3));
                    sc[kt][0] = __builtin_amdgcn_mfma_f32_16x16x32_bf16(kf, qfr[0][c], sc[kt][0], 0, 0, 0);
                    sc[kt][1] = __builtin_amdgcn_mfma_f32_16x16x32_bf16(kf, qfr[1][c], sc[kt][1], 0, 0, 0);
                }
            }

            if (kb + 32 > qw) {                        // diagonal tiles only
#pragma unroll
                for (int kt = 0; kt < 2; kt++)
#pragma unroll
                    for (int qi = 0; qi < 2; qi++)
#pragma unroll
                        for (int g = 0; g < 4; g++) {
                            const int key = kb + kt * 16 + q4 * 4 + g;
                            if (key > qw + qi * 16 + qcol) sc[kt][qi][g] = -1e30f;
                        }
            }

            const unsigned sel = 0x07060302u;
#pragma unroll
            for (int qi = 0; qi < 2; qi++) {
                float p0 = EXP2(sc[0][qi][0]), p1 = EXP2(sc[0][qi][1]);
                float p2 = EXP2(sc[0][qi][2]), p3 = EXP2(sc[0][qi][3]);
                float p4 = EXP2(sc[1][qi][0]), p5 = EXP2(sc[1][qi][1]);
                float p6 = EXP2(sc[1][qi][2]), p7 = EXP2(sc[1][qi][3]);
                unsigned pk0 = __builtin_amdgcn_perm(__float_as_uint(p1), __float_as_uint(p0), sel);
                unsigned pk1 = __builtin_amdgcn_perm(__float_as_uint(p3), __float_as_uint(p2), sel);
                unsigned pk2 = __builtin_amdgcn_perm(__float_as_uint(p5), __float_as_uint(p4), sel);
                unsigned pk3 = __builtin_amdgcn_perm(__float_as_uint(p7), __float_as_uint(p6), sel);
                const int row = qi * 16 + qcol;
                *(uint2*)(pb32 + row * 20 + 2 * q4)     = make_uint2(pk0, pk1);
                *(uint2*)(pb32 + row * 20 + 8 + 2 * q4) = make_uint2(pk2, pk3);
            }

            short8 pf0 = *(const short8*)(pb + qcol * 40 + q4 * 8);
            short8 pf1 = *(const short8*)(pb + (16 + qcol) * 40 + q4 * 8);

            lacc[0] = __builtin_amdgcn_mfma_f32_16x16x32_bf16(ones, pf0, lacc[0], 0, 0, 0);
            lacc[1] = __builtin_amdgcn_mfma_f32_16x16x32_bf16(ones, pf1, lacc[1], 0, 0, 0);
#pragma unroll
            for (int dt = 0; dt < 8; dt++) {
                const int vr = dt * 16 + qcol;
                short8 vfr = *(const short8*)(Vs + vr * 32 + ((q4 ^ ((vr >> 1) & 3)) << 3));
                oacc[0][dt] = __builtin_amdgcn_mfma_f32_16x16x32_bf16(vfr, pf0, oacc[0][dt], 0, 0, 0);
                oacc[1][dt] = __builtin_amdgcn_mfma_f32_16x16x32_bf16(vfr, pf1, oacc[1][dt], 0, 0, 0);
            }
        }
        __syncthreads();
    }

#pragma unroll
    for (int qi = 0; qi < 2; qi++) {
        const float inv = 1.0f / lacc[qi][0];
        u16* outp = Ctx + ((size_t)b * SS + qw + qi * 16 + qcol) * (NH * DD) + h * DD;
#pragma unroll
        for (int dt = 0; dt < 8; dt++) {
            unsigned lo = (unsigned)f2bf(oacc[qi][dt][0] * inv) | ((unsigned)f2bf(oacc[qi][dt][1] * inv) << 16);
            unsigned hi = (unsigned)f2bf(oacc[qi][dt][2] * inv) | ((unsigned)f2bf(oacc[qi][dt][3] * inv) << 16);
            *(uint2*)(outp + dt * 16 + q4 * 4) = make_uint2(lo, hi);
        }
    }
}

extern "C" void kernel_launch(void* const* d_in, const int* in_sizes, int n_in,
                              void* d_out, int out_size, void* d_ws, size_t ws_size,
                              hipStream_t stream) {
    const float* query = (const float*)d_in[0];
    const float* key   = (const float*)d_in[1];
    const float* value = (const float*)d_in[2];
    const float* fc    = (const float*)d_in[4];
    const float* fs    = (const float*)d_in[5];
    const float* Wq    = (const float*)d_in[6];
    const float* bq    = (const float*)d_in[7];
    const float* Wk    = (const float*)d_in[8];
    const float* bk    = (const float*)d_in[9];
    const float* Wv    = (const float*)d_in[10];
    const float* bv    = (const float*)d_in[11];
    const float* Wo    = (const float*)d_in[12];
    const float* bo    = (const float*)d_in[13];
    float* out = (float*)d_out;

    char* w = (char*)d_ws;
    u16* qbf = (u16*)(w);                    // 16 MB  bf16 query [4096][2048]
    u16* kbf = (u16*)(w + 16777216);         // 16 MB
    u16* vbf = (u16*)(w + 33554432);         // 16 MB
    u16* Wt  = (u16*)(w + 50331648);         // 12 MB  [Wq|Wk|Wv]^T bf16 [3072][2048]
    u16* Wot = (u16*)(w + 62914560);         //  8 MB  Wo^T bf16 [2048][2048]
    u16* qro = (u16*)(w + 71303168);         // 16 MB  roped+scaled q bf16 [B][H][S][D]
    u16* kro = (u16*)(w + 88080384);         //  4 MB  roped k bf16 [B][KV][S][D]
    u16* vtr = (u16*)(w + 92274688);         //  4 MB  v bf16 [B][KV][D][S]
    u16* ctx = (u16*)(w + 96468992);         // 16 MB  ctx bf16 [4096][2048]  (end 108 MB)

    k_prep<<<34816, 256, 0, stream>>>(query, key, value, Wq, Wk, Wv, Wo,
                                      qbf, kbf, vbf, Wt, Wot);
    k_gemm_qkv<<<dim3(24, 32), 256, 0, stream>>>(qbf, kbf, vbf, Wt, bq, bk, bv,
                                                 fc, fs, qro, kro, vtr);
    k_attn<<<dim3(32, 16), 256, 0, stream>>>(qro, kro, vtr, ctx);
    k_gemm_bt<<<dim3(16, 32), 256, 0, stream>>>(ctx, Wot, bo, out, 4096, 2048, 2048);
}